// Round 10
// baseline (1659.153 us; speedup 1.0000x reference)
//
#include <hip/hip_runtime.h>

#define F 64
#define TPB 256
#define SCAN_B 64
#define BN_EPS 1e-5f

typedef unsigned short u16;

__device__ __forceinline__ float lane_bcast(float v, int l) {
    return __int_as_float(__builtin_amdgcn_readlane(__float_as_int(v), l));
}
__device__ __forceinline__ int lane_bcast_i(int v, int l) {
    return __builtin_amdgcn_readlane(v, l);
}
__device__ __forceinline__ float bf2f(u16 u) {
    return __uint_as_float(((unsigned int)u) << 16);
}
__device__ __forceinline__ u16 f2bf(float f) {
    unsigned int u = __float_as_uint(f);
    unsigned int r = (u + 0x7fffu + ((u >> 16) & 1u)) >> 16;   // RNE
    return (u16)r;
}

// ---- CSR build ----------------------------------------------------------

__global__ __launch_bounds__(TPB) void k_hist(const int* __restrict__ dst,
                                              int* __restrict__ deg, int E) {
    int e = blockIdx.x * blockDim.x + threadIdx.x;
    if (e < E) atomicAdd(&deg[dst[e]], 1);
}

__global__ __launch_bounds__(TPB) void k_scan_part(const int* __restrict__ deg,
                                                   int* __restrict__ part, int N) {
    __shared__ int red[TPB];
    int chunk = (N + SCAN_B - 1) / SCAN_B;
    int lo = blockIdx.x * chunk, hi = min(lo + chunk, N);
    int t = threadIdx.x;
    int s = 0;
    for (int i = lo + t; i < hi; i += TPB) s += deg[i];
    red[t] = s; __syncthreads();
    for (int d = TPB / 2; d > 0; d >>= 1) {
        if (t < d) red[t] += red[t + d];
        __syncthreads();
    }
    if (t == 0) part[blockIdx.x] = red[0];
}

__global__ __launch_bounds__(TPB) void k_scan_apply(const int* __restrict__ deg,
                                                    const int* __restrict__ part,
                                                    int* __restrict__ offs,
                                                    int* __restrict__ cursor, int N) {
    __shared__ int ts[TPB];
    __shared__ int pb_s;
    int t = threadIdx.x;
    ts[t] = (t < blockIdx.x) ? part[t] : 0;
    __syncthreads();
    for (int d = TPB / 2; d > 0; d >>= 1) {
        if (t < d) ts[t] += ts[t + d];
        __syncthreads();
    }
    if (t == 0) pb_s = ts[0];
    __syncthreads();
    int pbase = pb_s;
    __syncthreads();
    int chunk = (N + SCAN_B - 1) / SCAN_B;
    int sub = (chunk + TPB - 1) / TPB;
    int lo = blockIdx.x * chunk;
    int blockhi = min(lo + chunk, N);
    int mylo = min(lo + t * sub, blockhi);
    int myhi = min(mylo + sub, blockhi);
    int s = 0;
    for (int i = mylo; i < myhi; ++i) s += deg[i];
    ts[t] = s; __syncthreads();
    for (int d = 1; d < TPB; d <<= 1) {
        int a = (t >= d) ? ts[t - d] : 0;
        __syncthreads();
        ts[t] += a;
        __syncthreads();
    }
    int run = pbase + ts[t] - s;
    for (int i = mylo; i < myhi; ++i) {
        offs[i] = run; cursor[i] = run; run += deg[i];
    }
    if (blockIdx.x == SCAN_B - 1 && t == TPB - 1) offs[N] = pbase + ts[TPB - 1];
}

__global__ __launch_bounds__(TPB) void k_fill(const int* __restrict__ src,
                                              const int* __restrict__ dst,
                                              int* __restrict__ cursor,
                                              int* __restrict__ csr_src, int E) {
    int e = blockIdx.x * blockDim.x + threadIdx.x;
    if (e >= E) return;
    int pos = atomicAdd(&cursor[dst[e]], 1);
    csr_src[pos] = src[e];
}

// ---- prep: x16 = bf16(x); Yf = x @ Wj + bias (fused, reads x once) ------
__global__ __launch_bounds__(TPB, 4)
void k_prep(const float* __restrict__ x, u16* __restrict__ x16,
            const float* __restrict__ Wj, const float* __restrict__ bias,
            float* __restrict__ Yf, int N, int rowsPerWave) {
    int t = threadIdx.x;
    int lane = t & 63, w = t >> 6;
    float wcol[F];
#pragma unroll
    for (int f = 0; f < F; ++f) wcol[f] = Wj[f * F + lane];
    float bj = bias[lane];
    int row0 = (blockIdx.x * 4 + w) * rowsPerWave;
    for (int r = 0; r < rowsPerWave; ++r) {
        int row = row0 + r;
        if (row >= N) break;
        float v = x[(size_t)row * F + lane];
        x16[(size_t)row * F + lane] = f2bf(v);
        float acc = bj;
#pragma unroll
        for (int f = 0; f < F; ++f) acc += lane_bcast(v, f) * wcol[f];
        Yf[(size_t)row * F + lane] = acc;
    }
}

// ---- fused gather + GEMM1 + BN stats (bf16 h rows, readlane gather) -----
// launch_bounds(256,8): VGPR<=64 (measured 52) -> 8 waves/SIMD for latency hiding
__global__ __launch_bounds__(TPB, 8)
void k_gather_gemm(const u16* __restrict__ h, const int* __restrict__ offs,
                   const int* __restrict__ csr,
                   const float* __restrict__ W, const float* __restrict__ bias,
                   float* __restrict__ Y, float* __restrict__ stats,
                   int N, int nodesPerWave) {
    int t = threadIdx.x;
    int lane = t & 63, w = t >> 6;
    float bj = bias[lane];
    int node0 = (blockIdx.x * 4 + w) * nodesPerWave;
    float s1 = 0.f, s2 = 0.f;
    for (int r = 0; r < nodesPerWave; ++r) {
        int node = node0 + r;
        if (node >= N) break;
        float agg = bf2f(h[(size_t)node * F + lane]);    // GIN self term (eps=0)
        int start = offs[node], end = offs[node + 1];
        for (int base = start; base < end; base += 64) {
            int cnt = end - base; if (cnt > 64) cnt = 64;
            int idx = (lane < cnt) ? csr[base + lane] : 0;
            int k = 0;
            for (; k + 8 <= cnt; k += 8) {               // 8 loads in flight
                int n0 = lane_bcast_i(idx, k),     n1 = lane_bcast_i(idx, k + 1);
                int n2 = lane_bcast_i(idx, k + 2), n3 = lane_bcast_i(idx, k + 3);
                int n4 = lane_bcast_i(idx, k + 4), n5 = lane_bcast_i(idx, k + 5);
                int n6 = lane_bcast_i(idx, k + 6), n7 = lane_bcast_i(idx, k + 7);
                float v0 = bf2f(h[(size_t)n0 * F + lane]);
                float v1 = bf2f(h[(size_t)n1 * F + lane]);
                float v2 = bf2f(h[(size_t)n2 * F + lane]);
                float v3 = bf2f(h[(size_t)n3 * F + lane]);
                float v4 = bf2f(h[(size_t)n4 * F + lane]);
                float v5 = bf2f(h[(size_t)n5 * F + lane]);
                float v6 = bf2f(h[(size_t)n6 * F + lane]);
                float v7 = bf2f(h[(size_t)n7 * F + lane]);
                agg += ((v0 + v1) + (v2 + v3)) + ((v4 + v5) + (v6 + v7));
            }
            for (; k < cnt; ++k)
                agg += bf2f(h[(size_t)lane_bcast_i(idx, k) * F + lane]);
        }
        float acc = bj;
#pragma unroll
        for (int f = 0; f < F; ++f) acc += lane_bcast(agg, f) * W[f * F + lane];
        Y[(size_t)node * F + lane] = acc;
        s1 += acc;
        s2 += acc * acc;
    }
    __shared__ float red[TPB];
    red[t] = s1; __syncthreads();
    if (w == 0) atomicAdd(&stats[lane], red[lane] + red[64 + lane] + red[128 + lane] + red[192 + lane]);
    __syncthreads();
    red[t] = s2; __syncthreads();
    if (w == 0) atomicAdd(&stats[64 + lane], red[lane] + red[64 + lane] + red[128 + lane] + red[192 + lane]);
}

// ---- fused: BN(Y)+ReLU -> GEMM2 -> ReLU -> Hout(bf16); Yf += Hout @ Wj --
__global__ __launch_bounds__(TPB, 3)
void k_layerB(const float* __restrict__ Y, const float* __restrict__ stats,
              const float* __restrict__ g, const float* __restrict__ bt,
              const float* __restrict__ W2, const float* __restrict__ b2,
              const float* __restrict__ Wj,
              u16* __restrict__ Hout, float* __restrict__ Yf,
              float* __restrict__ stats5, int N, int rowsPerWave, int doHead) {
    int t = threadIdx.x;
    int lane = t & 63, w = t >> 6;
    float wc2[F], wcj[F];
#pragma unroll
    for (int f = 0; f < F; ++f) { wc2[f] = W2[f * F + lane]; wcj[f] = Wj[f * F + lane]; }
    float mu = stats[lane] / (float)N;
    float var = stats[64 + lane] / (float)N - mu * mu;
    float rs = rsqrtf(var + BN_EPS);
    float sc = rs * g[lane];
    float sh = bt[lane] - mu * sc;
    float bj = b2[lane];
    int row0 = (blockIdx.x * 4 + w) * rowsPerWave;
    float s1 = 0.f, s2 = 0.f;
    for (int r = 0; r < rowsPerWave; ++r) {
        int row = row0 + r;
        if (row >= N) break;
        float v = fmaxf(Y[(size_t)row * F + lane] * sc + sh, 0.f);
        float acc = bj;
#pragma unroll
        for (int f = 0; f < F; ++f) acc += lane_bcast(v, f) * wc2[f];
        float hv = fmaxf(acc, 0.f);
        Hout[(size_t)row * F + lane] = f2bf(hv);
        float yf = Yf[(size_t)row * F + lane];
#pragma unroll
        for (int f = 0; f < F; ++f) yf += lane_bcast(hv, f) * wcj[f];
        Yf[(size_t)row * F + lane] = yf;
        if (doHead) { s1 += yf; s2 += yf * yf; }
    }
    if (doHead) {
        __shared__ float red[TPB];
        red[t] = s1; __syncthreads();
        if (w == 0) atomicAdd(&stats5[lane], red[lane] + red[64 + lane] + red[128 + lane] + red[192 + lane]);
        __syncthreads();
        red[t] = s2; __syncthreads();
        if (w == 0) atomicAdd(&stats5[64 + lane], red[lane] + red[64 + lane] + red[128 + lane] + red[192 + lane]);
    }
}

// ---- head: BN(Yf)+ReLU -> @mlpW2+b2 -> pooled add into out[graph] -------
__global__ __launch_bounds__(TPB, 4)
void k_final(const float* __restrict__ Yf, const float* __restrict__ stats,
             const float* __restrict__ g, const float* __restrict__ bt,
             const float* __restrict__ W2, const float* __restrict__ b2,
             const int* __restrict__ batch, float* __restrict__ out,
             int N, int rowsPerWave) {
    int t = threadIdx.x;
    int lane = t & 63, w = t >> 6;
    float wcol[F];
#pragma unroll
    for (int f = 0; f < F; ++f) wcol[f] = W2[f * F + lane];
    float mu = stats[lane] / (float)N;
    float var = stats[64 + lane] / (float)N - mu * mu;
    float rs = rsqrtf(var + BN_EPS);
    float sc = rs * g[lane];
    float sh = bt[lane] - mu * sc;
    float bj = b2[lane];
    int row0 = (blockIdx.x * 4 + w) * rowsPerWave;
    int curg = -1;
    float accg = 0.f;
    for (int r = 0; r < rowsPerWave; ++r) {
        int row = row0 + r;
        if (row >= N) break;
        float v = fmaxf(Yf[(size_t)row * F + lane] * sc + sh, 0.f);
        float acc = bj;
#pragma unroll
        for (int f = 0; f < F; ++f) acc += lane_bcast(v, f) * wcol[f];
        int gid = batch[row];
        if (gid != curg) {
            if (curg >= 0) atomicAdd(&out[(size_t)curg * F + lane], accg);
            curg = gid;
            accg = 0.f;
        }
        accg += acc;
    }
    if (curg >= 0) atomicAdd(&out[(size_t)curg * F + lane], accg);
}

// ---- launcher -----------------------------------------------------------

extern "C" void kernel_launch(void* const* d_in, const int* in_sizes, int n_in,
                              void* d_out, int out_size, void* d_ws, size_t ws_size,
                              hipStream_t stream) {
    const float* x      = (const float*)d_in[0];
    const int*   ei     = (const int*)d_in[1];
    const int*   batch  = (const int*)d_in[2];
    const float* convW1 = (const float*)d_in[3];
    const float* convb1 = (const float*)d_in[4];
    const float* convg  = (const float*)d_in[5];
    const float* convbt = (const float*)d_in[6];
    const float* convW2 = (const float*)d_in[7];
    const float* convb2 = (const float*)d_in[8];
    const float* mlpW1  = (const float*)d_in[9];
    const float* mlpb1  = (const float*)d_in[10];
    const float* mlpg   = (const float*)d_in[11];
    const float* mlpbt  = (const float*)d_in[12];
    const float* mlpW2  = (const float*)d_in[13];
    const float* mlpb2  = (const float*)d_in[14];

    const int N = in_sizes[0] / F;             // 50000
    const int E = in_sizes[1] / 2;             // 800000
    const int L = in_sizes[3] / (F * F);       // 5

    const int* src = ei;
    const int* dst = ei + E;

    char* w = (char*)d_ws;
    size_t off = 0;
    auto alloc = [&](size_t bytes) {
        void* p = w + off;
        off = (off + bytes + 255) & ~(size_t)255;
        return p;
    };
    u16*   x16     = (u16*)alloc((size_t)N * F * 2);
    u16*   hA16    = (u16*)alloc((size_t)N * F * 2);
    u16*   hB16    = (u16*)alloc((size_t)N * F * 2);
    float* Ytmp    = (float*)alloc((size_t)N * F * 4);
    float* Yf      = (float*)alloc((size_t)N * F * 4);
    int*   deg     = (int*)alloc((size_t)N * 4);
    int*   offs    = (int*)alloc((size_t)(N + 1) * 4);
    int*   cursor  = (int*)alloc((size_t)N * 4);
    int*   csr_src = (int*)alloc((size_t)E * 4);
    int*   part    = (int*)alloc((size_t)SCAN_B * 4);
    float* stats   = (float*)alloc((size_t)(L + 1) * 128 * 4);

    hipMemsetAsync(deg, 0, (size_t)N * 4, stream);
    hipMemsetAsync(stats, 0, (size_t)(L + 1) * 128 * 4, stream);
    hipMemsetAsync(d_out, 0, (size_t)out_size * 4, stream);

    const int edgeBlocks = (E + TPB - 1) / TPB;

    k_hist<<<edgeBlocks, TPB, 0, stream>>>(dst, deg, E);
    k_scan_part<<<SCAN_B, TPB, 0, stream>>>(deg, part, N);
    k_scan_apply<<<SCAN_B, TPB, 0, stream>>>(deg, part, offs, cursor, N);
    k_fill<<<edgeBlocks, TPB, 0, stream>>>(src, dst, cursor, csr_src, E);

    const int NPW_A = 8;
    const int RPW   = 8;
    const int RPW_F = 16;
    const int blocksA = (N + 4 * NPW_A - 1) / (4 * NPW_A);
    const int blocksD = (N + 4 * RPW - 1) / (4 * RPW);
    const int blocksF = (N + 4 * RPW_F - 1) / (4 * RPW_F);

    // fused bf16-convert + JK-init (reads x once)
    k_prep<<<blocksD, TPB, 0, stream>>>(x, x16, mlpW1, mlpb1, Yf, N, RPW);

    const u16* h_cur = x16;
    for (int l = 0; l < L; ++l) {
        u16* h_next = (l & 1) ? hB16 : hA16;
        k_gather_gemm<<<blocksA, TPB, 0, stream>>>(h_cur, offs, csr_src,
                                                   convW1 + l * F * F, convb1 + l * F,
                                                   Ytmp, stats + l * 128, N, NPW_A);
        k_layerB<<<blocksD, TPB, 0, stream>>>(Ytmp, stats + l * 128,
                                              convg + l * F, convbt + l * F,
                                              convW2 + l * F * F, convb2 + l * F,
                                              mlpW1 + (l + 1) * F * F,
                                              h_next, Yf, stats + L * 128,
                                              N, RPW, l == L - 1);
        h_cur = h_next;
    }

    k_final<<<blocksF, TPB, 0, stream>>>(Yf, stats + L * 128, mlpg, mlpbt,
                                         mlpW2, mlpb2, batch, (float*)d_out, N, RPW_F);
}

// Round 11
// 767.561 us; speedup vs baseline: 2.1616x; 2.1616x over previous
//
#include <hip/hip_runtime.h>

#define F 64
#define TPB 256
#define SCAN_B 64
#define BN_EPS 1e-5f

typedef unsigned short u16;

__device__ __forceinline__ float lane_bcast(float v, int l) {
    return __int_as_float(__builtin_amdgcn_readlane(__float_as_int(v), l));
}
__device__ __forceinline__ int lane_bcast_i(int v, int l) {
    return __builtin_amdgcn_readlane(v, l);
}
__device__ __forceinline__ float bf2f(u16 u) {
    return __uint_as_float(((unsigned int)u) << 16);
}
__device__ __forceinline__ u16 f2bf(float f) {
    unsigned int u = __float_as_uint(f);
    unsigned int r = (u + 0x7fffu + ((u >> 16) & 1u)) >> 16;   // RNE
    return (u16)r;
}

// ---- CSR build ----------------------------------------------------------

__global__ __launch_bounds__(TPB) void k_hist(const int* __restrict__ dst,
                                              int* __restrict__ deg, int E) {
    int e = blockIdx.x * blockDim.x + threadIdx.x;
    if (e < E) atomicAdd(&deg[dst[e]], 1);
}

__global__ __launch_bounds__(TPB) void k_scan_part(const int* __restrict__ deg,
                                                   int* __restrict__ part, int N) {
    __shared__ int red[TPB];
    int chunk = (N + SCAN_B - 1) / SCAN_B;
    int lo = blockIdx.x * chunk, hi = min(lo + chunk, N);
    int t = threadIdx.x;
    int s = 0;
    for (int i = lo + t; i < hi; i += TPB) s += deg[i];
    red[t] = s; __syncthreads();
    for (int d = TPB / 2; d > 0; d >>= 1) {
        if (t < d) red[t] += red[t + d];
        __syncthreads();
    }
    if (t == 0) part[blockIdx.x] = red[0];
}

__global__ __launch_bounds__(TPB) void k_scan_apply(const int* __restrict__ deg,
                                                    const int* __restrict__ part,
                                                    int* __restrict__ offs,
                                                    int* __restrict__ cursor, int N) {
    __shared__ int ts[TPB];
    __shared__ int pb_s;
    int t = threadIdx.x;
    ts[t] = (t < blockIdx.x) ? part[t] : 0;
    __syncthreads();
    for (int d = TPB / 2; d > 0; d >>= 1) {
        if (t < d) ts[t] += ts[t + d];
        __syncthreads();
    }
    if (t == 0) pb_s = ts[0];
    __syncthreads();
    int pbase = pb_s;
    __syncthreads();
    int chunk = (N + SCAN_B - 1) / SCAN_B;
    int sub = (chunk + TPB - 1) / TPB;
    int lo = blockIdx.x * chunk;
    int blockhi = min(lo + chunk, N);
    int mylo = min(lo + t * sub, blockhi);
    int myhi = min(mylo + sub, blockhi);
    int s = 0;
    for (int i = mylo; i < myhi; ++i) s += deg[i];
    ts[t] = s; __syncthreads();
    for (int d = 1; d < TPB; d <<= 1) {
        int a = (t >= d) ? ts[t - d] : 0;
        __syncthreads();
        ts[t] += a;
        __syncthreads();
    }
    int run = pbase + ts[t] - s;
    for (int i = mylo; i < myhi; ++i) {
        offs[i] = run; cursor[i] = run; run += deg[i];
    }
    if (blockIdx.x == SCAN_B - 1 && t == TPB - 1) offs[N] = pbase + ts[TPB - 1];
}

__global__ __launch_bounds__(TPB) void k_fill(const int* __restrict__ src,
                                              const int* __restrict__ dst,
                                              int* __restrict__ cursor,
                                              int* __restrict__ csr_src, int E) {
    int e = blockIdx.x * blockDim.x + threadIdx.x;
    if (e >= E) return;
    int pos = atomicAdd(&cursor[dst[e]], 1);
    csr_src[pos] = src[e];
}

// ---- prep: x16 = bf16(x); Yf = x @ Wj + bias (fused, reads x once) ------
__global__ __launch_bounds__(TPB, 4)
void k_prep(const float* __restrict__ x, u16* __restrict__ x16,
            const float* __restrict__ Wj, const float* __restrict__ bias,
            float* __restrict__ Yf, int N, int rowsPerWave) {
    int t = threadIdx.x;
    int lane = t & 63, w = t >> 6;
    float wcol[F];
#pragma unroll
    for (int f = 0; f < F; ++f) wcol[f] = Wj[f * F + lane];
    float bj = bias[lane];
    int row0 = (blockIdx.x * 4 + w) * rowsPerWave;
    for (int r = 0; r < rowsPerWave; ++r) {
        int row = row0 + r;
        if (row >= N) break;
        float v = x[(size_t)row * F + lane];
        x16[(size_t)row * F + lane] = f2bf(v);
        float acc = bj;
#pragma unroll
        for (int f = 0; f < F; ++f) acc += lane_bcast(v, f) * wcol[f];
        Yf[(size_t)row * F + lane] = acc;
    }
}

// ---- fused gather + GEMM1 + BN stats ------------------------------------
// LB(256,4): 128-VGPR budget, no spills (R10 lesson: LB=8 spills -> 10x traffic).
// 16-deep load batch: avg degree 16 -> one batch per node, halves latency waits.
__global__ __launch_bounds__(TPB, 4)
void k_gather_gemm(const u16* __restrict__ h, const int* __restrict__ offs,
                   const int* __restrict__ csr,
                   const float* __restrict__ W, const float* __restrict__ bias,
                   float* __restrict__ Y, float* __restrict__ stats,
                   int N, int nodesPerWave) {
    int t = threadIdx.x;
    int lane = t & 63, w = t >> 6;
    float wcol[F];
#pragma unroll
    for (int f = 0; f < F; ++f) wcol[f] = W[f * F + lane];
    float bj = bias[lane];
    int node0 = (blockIdx.x * 4 + w) * nodesPerWave;
    float s1 = 0.f, s2 = 0.f;
    for (int r = 0; r < nodesPerWave; ++r) {
        int node = node0 + r;
        if (node >= N) break;
        float agg = bf2f(h[(size_t)node * F + lane]);    // GIN self term (eps=0)
        int start = offs[node], end = offs[node + 1];
        for (int base = start; base < end; base += 64) {
            int cnt = end - base; if (cnt > 64) cnt = 64;
            int idx = (lane < cnt) ? csr[base + lane] : 0;
            int k = 0;
            for (; k + 16 <= cnt; k += 16) {             // 16 loads in flight
                float vv[16];
#pragma unroll
                for (int u = 0; u < 16; ++u)
                    vv[u] = bf2f(h[(size_t)lane_bcast_i(idx, k + u) * F + lane]);
                float sA = 0.f, sB = 0.f, sC = 0.f, sD = 0.f;
#pragma unroll
                for (int u = 0; u < 4; ++u) {
                    sA += vv[u];
                    sB += vv[4 + u];
                    sC += vv[8 + u];
                    sD += vv[12 + u];
                }
                agg += (sA + sB) + (sC + sD);
            }
            for (; k + 4 <= cnt; k += 4) {
                float v0 = bf2f(h[(size_t)lane_bcast_i(idx, k)     * F + lane]);
                float v1 = bf2f(h[(size_t)lane_bcast_i(idx, k + 1) * F + lane]);
                float v2 = bf2f(h[(size_t)lane_bcast_i(idx, k + 2) * F + lane]);
                float v3 = bf2f(h[(size_t)lane_bcast_i(idx, k + 3) * F + lane]);
                agg += (v0 + v1) + (v2 + v3);
            }
            for (; k < cnt; ++k)
                agg += bf2f(h[(size_t)lane_bcast_i(idx, k) * F + lane]);
        }
        float acc = bj;
#pragma unroll
        for (int f = 0; f < F; ++f) acc += lane_bcast(agg, f) * wcol[f];
        Y[(size_t)node * F + lane] = acc;
        s1 += acc;
        s2 += acc * acc;
    }
    __shared__ float red[TPB];
    red[t] = s1; __syncthreads();
    if (w == 0) atomicAdd(&stats[lane], red[lane] + red[64 + lane] + red[128 + lane] + red[192 + lane]);
    __syncthreads();
    red[t] = s2; __syncthreads();
    if (w == 0) atomicAdd(&stats[64 + lane], red[lane] + red[64 + lane] + red[128 + lane] + red[192 + lane]);
}

// ---- fused: BN(Y)+ReLU -> GEMM2 -> ReLU -> Hout(bf16); Yf += Hout @ Wj --
__global__ __launch_bounds__(TPB, 3)
void k_layerB(const float* __restrict__ Y, const float* __restrict__ stats,
              const float* __restrict__ g, const float* __restrict__ bt,
              const float* __restrict__ W2, const float* __restrict__ b2,
              const float* __restrict__ Wj,
              u16* __restrict__ Hout, float* __restrict__ Yf,
              float* __restrict__ stats5, int N, int rowsPerWave, int doHead) {
    int t = threadIdx.x;
    int lane = t & 63, w = t >> 6;
    float wc2[F], wcj[F];
#pragma unroll
    for (int f = 0; f < F; ++f) { wc2[f] = W2[f * F + lane]; wcj[f] = Wj[f * F + lane]; }
    float mu = stats[lane] / (float)N;
    float var = stats[64 + lane] / (float)N - mu * mu;
    float rs = rsqrtf(var + BN_EPS);
    float sc = rs * g[lane];
    float sh = bt[lane] - mu * sc;
    float bj = b2[lane];
    int row0 = (blockIdx.x * 4 + w) * rowsPerWave;
    float s1 = 0.f, s2 = 0.f;
    for (int r = 0; r < rowsPerWave; ++r) {
        int row = row0 + r;
        if (row >= N) break;
        float v = fmaxf(Y[(size_t)row * F + lane] * sc + sh, 0.f);
        float acc = bj;
#pragma unroll
        for (int f = 0; f < F; ++f) acc += lane_bcast(v, f) * wc2[f];
        float hv = fmaxf(acc, 0.f);
        Hout[(size_t)row * F + lane] = f2bf(hv);
        float yf = Yf[(size_t)row * F + lane];
#pragma unroll
        for (int f = 0; f < F; ++f) yf += lane_bcast(hv, f) * wcj[f];
        Yf[(size_t)row * F + lane] = yf;
        if (doHead) { s1 += yf; s2 += yf * yf; }
    }
    if (doHead) {
        __shared__ float red[TPB];
        red[t] = s1; __syncthreads();
        if (w == 0) atomicAdd(&stats5[lane], red[lane] + red[64 + lane] + red[128 + lane] + red[192 + lane]);
        __syncthreads();
        red[t] = s2; __syncthreads();
        if (w == 0) atomicAdd(&stats5[64 + lane], red[lane] + red[64 + lane] + red[128 + lane] + red[192 + lane]);
    }
}

// ---- head: BN(Yf)+ReLU -> @mlpW2+b2 -> pooled add into out[graph] -------
__global__ __launch_bounds__(TPB, 4)
void k_final(const float* __restrict__ Yf, const float* __restrict__ stats,
             const float* __restrict__ g, const float* __restrict__ bt,
             const float* __restrict__ W2, const float* __restrict__ b2,
             const int* __restrict__ batch, float* __restrict__ out,
             int N, int rowsPerWave) {
    int t = threadIdx.x;
    int lane = t & 63, w = t >> 6;
    float wcol[F];
#pragma unroll
    for (int f = 0; f < F; ++f) wcol[f] = W2[f * F + lane];
    float mu = stats[lane] / (float)N;
    float var = stats[64 + lane] / (float)N - mu * mu;
    float rs = rsqrtf(var + BN_EPS);
    float sc = rs * g[lane];
    float sh = bt[lane] - mu * sc;
    float bj = b2[lane];
    int row0 = (blockIdx.x * 4 + w) * rowsPerWave;
    int curg = -1;
    float accg = 0.f;
    for (int r = 0; r < rowsPerWave; ++r) {
        int row = row0 + r;
        if (row >= N) break;
        float v = fmaxf(Yf[(size_t)row * F + lane] * sc + sh, 0.f);
        float acc = bj;
#pragma unroll
        for (int f = 0; f < F; ++f) acc += lane_bcast(v, f) * wcol[f];
        int gid = batch[row];
        if (gid != curg) {
            if (curg >= 0) atomicAdd(&out[(size_t)curg * F + lane], accg);
            curg = gid;
            accg = 0.f;
        }
        accg += acc;
    }
    if (curg >= 0) atomicAdd(&out[(size_t)curg * F + lane], accg);
}

// ---- launcher -----------------------------------------------------------

extern "C" void kernel_launch(void* const* d_in, const int* in_sizes, int n_in,
                              void* d_out, int out_size, void* d_ws, size_t ws_size,
                              hipStream_t stream) {
    const float* x      = (const float*)d_in[0];
    const int*   ei     = (const int*)d_in[1];
    const int*   batch  = (const int*)d_in[2];
    const float* convW1 = (const float*)d_in[3];
    const float* convb1 = (const float*)d_in[4];
    const float* convg  = (const float*)d_in[5];
    const float* convbt = (const float*)d_in[6];
    const float* convW2 = (const float*)d_in[7];
    const float* convb2 = (const float*)d_in[8];
    const float* mlpW1  = (const float*)d_in[9];
    const float* mlpb1  = (const float*)d_in[10];
    const float* mlpg   = (const float*)d_in[11];
    const float* mlpbt  = (const float*)d_in[12];
    const float* mlpW2  = (const float*)d_in[13];
    const float* mlpb2  = (const float*)d_in[14];

    const int N = in_sizes[0] / F;             // 50000
    const int E = in_sizes[1] / 2;             // 800000
    const int L = in_sizes[3] / (F * F);       // 5

    const int* src = ei;
    const int* dst = ei + E;

    char* w = (char*)d_ws;
    size_t off = 0;
    auto alloc = [&](size_t bytes) {
        void* p = w + off;
        off = (off + bytes + 255) & ~(size_t)255;
        return p;
    };
    u16*   x16     = (u16*)alloc((size_t)N * F * 2);
    u16*   hA16    = (u16*)alloc((size_t)N * F * 2);
    u16*   hB16    = (u16*)alloc((size_t)N * F * 2);
    float* Ytmp    = (float*)alloc((size_t)N * F * 4);
    float* Yf      = (float*)alloc((size_t)N * F * 4);
    int*   deg     = (int*)alloc((size_t)N * 4);
    int*   offs    = (int*)alloc((size_t)(N + 1) * 4);
    int*   cursor  = (int*)alloc((size_t)N * 4);
    int*   csr_src = (int*)alloc((size_t)E * 4);
    int*   part    = (int*)alloc((size_t)SCAN_B * 4);
    float* stats   = (float*)alloc((size_t)(L + 1) * 128 * 4);

    hipMemsetAsync(deg, 0, (size_t)N * 4, stream);
    hipMemsetAsync(stats, 0, (size_t)(L + 1) * 128 * 4, stream);
    hipMemsetAsync(d_out, 0, (size_t)out_size * 4, stream);

    const int edgeBlocks = (E + TPB - 1) / TPB;

    k_hist<<<edgeBlocks, TPB, 0, stream>>>(dst, deg, E);
    k_scan_part<<<SCAN_B, TPB, 0, stream>>>(deg, part, N);
    k_scan_apply<<<SCAN_B, TPB, 0, stream>>>(deg, part, offs, cursor, N);
    k_fill<<<edgeBlocks, TPB, 0, stream>>>(src, dst, cursor, csr_src, E);

    const int NPW_A = 8;
    const int RPW   = 8;
    const int RPW_F = 16;
    const int blocksA = (N + 4 * NPW_A - 1) / (4 * NPW_A);
    const int blocksD = (N + 4 * RPW - 1) / (4 * RPW);
    const int blocksF = (N + 4 * RPW_F - 1) / (4 * RPW_F);

    // fused bf16-convert + JK-init (reads x once)
    k_prep<<<blocksD, TPB, 0, stream>>>(x, x16, mlpW1, mlpb1, Yf, N, RPW);

    const u16* h_cur = x16;
    for (int l = 0; l < L; ++l) {
        u16* h_next = (l & 1) ? hB16 : hA16;
        k_gather_gemm<<<blocksA, TPB, 0, stream>>>(h_cur, offs, csr_src,
                                                   convW1 + l * F * F, convb1 + l * F,
                                                   Ytmp, stats + l * 128, N, NPW_A);
        k_layerB<<<blocksD, TPB, 0, stream>>>(Ytmp, stats + l * 128,
                                              convg + l * F, convbt + l * F,
                                              convW2 + l * F * F, convb2 + l * F,
                                              mlpW1 + (l + 1) * F * F,
                                              h_next, Yf, stats + L * 128,
                                              N, RPW, l == L - 1);
        h_cur = h_next;
    }

    k_final<<<blocksF, TPB, 0, stream>>>(Yf, stats + L * 128, mlpg, mlpbt,
                                         mlpW2, mlpb2, batch, (float*)d_out, N, RPW_F);
}

// Round 12
// 744.497 us; speedup vs baseline: 2.2286x; 1.0310x over previous
//
#include <hip/hip_runtime.h>

#define F 64
#define TPB 256
#define SCAN_B 64
#define BN_EPS 1e-5f

typedef unsigned short u16;

__device__ __forceinline__ float lane_bcast(float v, int l) {
    return __int_as_float(__builtin_amdgcn_readlane(__float_as_int(v), l));
}
__device__ __forceinline__ int lane_bcast_i(int v, int l) {
    return __builtin_amdgcn_readlane(v, l);
}
__device__ __forceinline__ float bf2f(u16 u) {
    return __uint_as_float(((unsigned int)u) << 16);
}
__device__ __forceinline__ u16 f2bf(float f) {
    unsigned int u = __float_as_uint(f);
    unsigned int r = (u + 0x7fffu + ((u >> 16) & 1u)) >> 16;   // RNE
    return (u16)r;
}

// ---- CSR build ----------------------------------------------------------

__global__ __launch_bounds__(TPB) void k_hist(const int* __restrict__ dst,
                                              int* __restrict__ deg, int E) {
    int e = blockIdx.x * blockDim.x + threadIdx.x;
    if (e < E) atomicAdd(&deg[dst[e]], 1);
}

__global__ __launch_bounds__(TPB) void k_scan_part(const int* __restrict__ deg,
                                                   int* __restrict__ part, int N) {
    __shared__ int red[TPB];
    int chunk = (N + SCAN_B - 1) / SCAN_B;
    int lo = blockIdx.x * chunk, hi = min(lo + chunk, N);
    int t = threadIdx.x;
    int s = 0;
    for (int i = lo + t; i < hi; i += TPB) s += deg[i];
    red[t] = s; __syncthreads();
    for (int d = TPB / 2; d > 0; d >>= 1) {
        if (t < d) red[t] += red[t + d];
        __syncthreads();
    }
    if (t == 0) part[blockIdx.x] = red[0];
}

__global__ __launch_bounds__(TPB) void k_scan_apply(const int* __restrict__ deg,
                                                    const int* __restrict__ part,
                                                    int* __restrict__ offs,
                                                    int* __restrict__ cursor, int N) {
    __shared__ int ts[TPB];
    __shared__ int pb_s;
    int t = threadIdx.x;
    ts[t] = (t < blockIdx.x) ? part[t] : 0;
    __syncthreads();
    for (int d = TPB / 2; d > 0; d >>= 1) {
        if (t < d) ts[t] += ts[t + d];
        __syncthreads();
    }
    if (t == 0) pb_s = ts[0];
    __syncthreads();
    int pbase = pb_s;
    __syncthreads();
    int chunk = (N + SCAN_B - 1) / SCAN_B;
    int sub = (chunk + TPB - 1) / TPB;
    int lo = blockIdx.x * chunk;
    int blockhi = min(lo + chunk, N);
    int mylo = min(lo + t * sub, blockhi);
    int myhi = min(mylo + sub, blockhi);
    int s = 0;
    for (int i = mylo; i < myhi; ++i) s += deg[i];
    ts[t] = s; __syncthreads();
    for (int d = 1; d < TPB; d <<= 1) {
        int a = (t >= d) ? ts[t - d] : 0;
        __syncthreads();
        ts[t] += a;
        __syncthreads();
    }
    int run = pbase + ts[t] - s;
    for (int i = mylo; i < myhi; ++i) {
        offs[i] = run; cursor[i] = run; run += deg[i];
    }
    if (blockIdx.x == SCAN_B - 1 && t == TPB - 1) offs[N] = pbase + ts[TPB - 1];
}

__global__ __launch_bounds__(TPB) void k_fill(const int* __restrict__ src,
                                              const int* __restrict__ dst,
                                              int* __restrict__ cursor,
                                              int* __restrict__ csr_src, int E) {
    int e = blockIdx.x * blockDim.x + threadIdx.x;
    if (e >= E) return;
    int pos = atomicAdd(&cursor[dst[e]], 1);
    csr_src[pos] = src[e];
}

// ---- prep: x16 = bf16(x); Yf = x @ Wj + bias (fused, reads x once) ------
__global__ __launch_bounds__(TPB, 4)
void k_prep(const float* __restrict__ x, u16* __restrict__ x16,
            const float* __restrict__ Wj, const float* __restrict__ bias,
            float* __restrict__ Yf, int N, int rowsPerWave) {
    int t = threadIdx.x;
    int lane = t & 63, w = t >> 6;
    float wcol[F];
#pragma unroll
    for (int f = 0; f < F; ++f) wcol[f] = Wj[f * F + lane];
    float bj = bias[lane];
    int row0 = (blockIdx.x * 4 + w) * rowsPerWave;
    for (int r = 0; r < rowsPerWave; ++r) {
        int row = row0 + r;
        if (row >= N) break;
        float v = x[(size_t)row * F + lane];
        x16[(size_t)row * F + lane] = f2bf(v);
        float acc = bj;
#pragma unroll
        for (int f = 0; f < F; ++f) acc += lane_bcast(v, f) * wcol[f];
        Yf[(size_t)row * F + lane] = acc;
    }
}

// ---- fused gather + GEMM1 + BN stats ------------------------------------
// Software-pipelined: offs for all 8 nodes loaded once via lanes; next node's
// index batch prefetched during current node's gather+GEMM. W in LDS (off the
// VMEM port; stride-64 f32 = 2-way bank aliasing = free).
__global__ __launch_bounds__(TPB, 4)
void k_gather_gemm(const u16* __restrict__ h, const int* __restrict__ offs,
                   const int* __restrict__ csr,
                   const float* __restrict__ W, const float* __restrict__ bias,
                   float* __restrict__ Y, float* __restrict__ stats,
                   int N, int nodesPerWave) {
    __shared__ float Wl[F * F];
    int t = threadIdx.x;
    int lane = t & 63, w = t >> 6;
    for (int i = t; i < F * F; i += TPB) Wl[i] = W[i];
    __syncthreads();
    float bj = bias[lane];
    int node0 = (blockIdx.x * 4 + w) * nodesPerWave;
    // offs[node0 .. node0+NPW] via lanes (clamped), broadcast later by readlane
    int off_l = 0;
    if (lane <= nodesPerWave) off_l = offs[min(node0 + lane, N)];
    float s1 = 0.f, s2 = 0.f;
    // prefetch node 0's first batch
    int start_n = lane_bcast_i(off_l, 0);
    int end_n   = lane_bcast_i(off_l, 1);
    int cnt_n   = min(end_n - start_n, 64);
    int idx_n   = (lane < cnt_n) ? csr[start_n + lane] : 0;
    for (int r = 0; r < nodesPerWave; ++r) {
        int node = node0 + r;
        if (node >= N) break;
        int start = start_n, end = end_n, cnt = cnt_n, idx = idx_n;
        // prefetch next node's first batch (clamped offs make this safe)
        if (r + 1 < nodesPerWave) {
            start_n = lane_bcast_i(off_l, r + 1);
            end_n   = lane_bcast_i(off_l, r + 2);
            cnt_n   = min(end_n - start_n, 64);
            idx_n   = (lane < cnt_n) ? csr[start_n + lane] : 0;
        }
        float agg = bf2f(h[(size_t)node * F + lane]);    // GIN self term (eps=0)
        // first batch (prefetched idx)
        {
            int k = 0;
            for (; k + 16 <= cnt; k += 16) {
                float vv[16];
#pragma unroll
                for (int u = 0; u < 16; ++u)
                    vv[u] = bf2f(h[(size_t)lane_bcast_i(idx, k + u) * F + lane]);
                float sA = 0.f, sB = 0.f, sC = 0.f, sD = 0.f;
#pragma unroll
                for (int u = 0; u < 4; ++u) {
                    sA += vv[u]; sB += vv[4 + u]; sC += vv[8 + u]; sD += vv[12 + u];
                }
                agg += (sA + sB) + (sC + sD);
            }
            for (; k + 4 <= cnt; k += 4) {
                float v0 = bf2f(h[(size_t)lane_bcast_i(idx, k)     * F + lane]);
                float v1 = bf2f(h[(size_t)lane_bcast_i(idx, k + 1) * F + lane]);
                float v2 = bf2f(h[(size_t)lane_bcast_i(idx, k + 2) * F + lane]);
                float v3 = bf2f(h[(size_t)lane_bcast_i(idx, k + 3) * F + lane]);
                agg += (v0 + v1) + (v2 + v3);
            }
            for (; k < cnt; ++k)
                agg += bf2f(h[(size_t)lane_bcast_i(idx, k) * F + lane]);
        }
        // remaining batches (degree > 64, rare)
        for (int base = start + 64; base < end; base += 64) {
            int c2 = end - base; if (c2 > 64) c2 = 64;
            int idx2 = (lane < c2) ? csr[base + lane] : 0;
            int k = 0;
            for (; k + 4 <= c2; k += 4) {
                float v0 = bf2f(h[(size_t)lane_bcast_i(idx2, k)     * F + lane]);
                float v1 = bf2f(h[(size_t)lane_bcast_i(idx2, k + 1) * F + lane]);
                float v2 = bf2f(h[(size_t)lane_bcast_i(idx2, k + 2) * F + lane]);
                float v3 = bf2f(h[(size_t)lane_bcast_i(idx2, k + 3) * F + lane]);
                agg += (v0 + v1) + (v2 + v3);
            }
            for (; k < c2; ++k)
                agg += bf2f(h[(size_t)lane_bcast_i(idx2, k) * F + lane]);
        }
        // GEMM from LDS W
        float acc = bj;
#pragma unroll
        for (int f = 0; f < F; ++f) acc += lane_bcast(agg, f) * Wl[f * F + lane];
        Y[(size_t)node * F + lane] = acc;
        s1 += acc;
        s2 += acc * acc;
    }
    __shared__ float red[TPB];
    red[t] = s1; __syncthreads();
    if (w == 0) atomicAdd(&stats[lane], red[lane] + red[64 + lane] + red[128 + lane] + red[192 + lane]);
    __syncthreads();
    red[t] = s2; __syncthreads();
    if (w == 0) atomicAdd(&stats[64 + lane], red[lane] + red[64 + lane] + red[128 + lane] + red[192 + lane]);
}

// ---- fused: BN(Y)+ReLU -> GEMM2 -> ReLU -> Hout(bf16); Yf += Hout @ Wj --
__global__ __launch_bounds__(TPB, 3)
void k_layerB(const float* __restrict__ Y, const float* __restrict__ stats,
              const float* __restrict__ g, const float* __restrict__ bt,
              const float* __restrict__ W2, const float* __restrict__ b2,
              const float* __restrict__ Wj,
              u16* __restrict__ Hout, float* __restrict__ Yf,
              float* __restrict__ stats5, int N, int rowsPerWave, int doHead) {
    int t = threadIdx.x;
    int lane = t & 63, w = t >> 6;
    float wc2[F], wcj[F];
#pragma unroll
    for (int f = 0; f < F; ++f) { wc2[f] = W2[f * F + lane]; wcj[f] = Wj[f * F + lane]; }
    float mu = stats[lane] / (float)N;
    float var = stats[64 + lane] / (float)N - mu * mu;
    float rs = rsqrtf(var + BN_EPS);
    float sc = rs * g[lane];
    float sh = bt[lane] - mu * sc;
    float bj = b2[lane];
    int row0 = (blockIdx.x * 4 + w) * rowsPerWave;
    float s1 = 0.f, s2 = 0.f;
    for (int r = 0; r < rowsPerWave; ++r) {
        int row = row0 + r;
        if (row >= N) break;
        float v = fmaxf(Y[(size_t)row * F + lane] * sc + sh, 0.f);
        float acc = bj;
#pragma unroll
        for (int f = 0; f < F; ++f) acc += lane_bcast(v, f) * wc2[f];
        float hv = fmaxf(acc, 0.f);
        Hout[(size_t)row * F + lane] = f2bf(hv);
        float yf = Yf[(size_t)row * F + lane];
#pragma unroll
        for (int f = 0; f < F; ++f) yf += lane_bcast(hv, f) * wcj[f];
        Yf[(size_t)row * F + lane] = yf;
        if (doHead) { s1 += yf; s2 += yf * yf; }
    }
    if (doHead) {
        __shared__ float red[TPB];
        red[t] = s1; __syncthreads();
        if (w == 0) atomicAdd(&stats5[lane], red[lane] + red[64 + lane] + red[128 + lane] + red[192 + lane]);
        __syncthreads();
        red[t] = s2; __syncthreads();
        if (w == 0) atomicAdd(&stats5[64 + lane], red[lane] + red[64 + lane] + red[128 + lane] + red[192 + lane]);
    }
}

// ---- head: BN(Yf)+ReLU -> @mlpW2+b2 -> pooled add into out[graph] -------
__global__ __launch_bounds__(TPB, 4)
void k_final(const float* __restrict__ Yf, const float* __restrict__ stats,
             const float* __restrict__ g, const float* __restrict__ bt,
             const float* __restrict__ W2, const float* __restrict__ b2,
             const int* __restrict__ batch, float* __restrict__ out,
             int N, int rowsPerWave) {
    int t = threadIdx.x;
    int lane = t & 63, w = t >> 6;
    float wcol[F];
#pragma unroll
    for (int f = 0; f < F; ++f) wcol[f] = W2[f * F + lane];
    float mu = stats[lane] / (float)N;
    float var = stats[64 + lane] / (float)N - mu * mu;
    float rs = rsqrtf(var + BN_EPS);
    float sc = rs * g[lane];
    float sh = bt[lane] - mu * sc;
    float bj = b2[lane];
    int row0 = (blockIdx.x * 4 + w) * rowsPerWave;
    int curg = -1;
    float accg = 0.f;
    for (int r = 0; r < rowsPerWave; ++r) {
        int row = row0 + r;
        if (row >= N) break;
        float v = fmaxf(Yf[(size_t)row * F + lane] * sc + sh, 0.f);
        float acc = bj;
#pragma unroll
        for (int f = 0; f < F; ++f) acc += lane_bcast(v, f) * wcol[f];
        int gid = batch[row];
        if (gid != curg) {
            if (curg >= 0) atomicAdd(&out[(size_t)curg * F + lane], accg);
            curg = gid;
            accg = 0.f;
        }
        accg += acc;
    }
    if (curg >= 0) atomicAdd(&out[(size_t)curg * F + lane], accg);
}

// ---- launcher -----------------------------------------------------------

extern "C" void kernel_launch(void* const* d_in, const int* in_sizes, int n_in,
                              void* d_out, int out_size, void* d_ws, size_t ws_size,
                              hipStream_t stream) {
    const float* x      = (const float*)d_in[0];
    const int*   ei     = (const int*)d_in[1];
    const int*   batch  = (const int*)d_in[2];
    const float* convW1 = (const float*)d_in[3];
    const float* convb1 = (const float*)d_in[4];
    const float* convg  = (const float*)d_in[5];
    const float* convbt = (const float*)d_in[6];
    const float* convW2 = (const float*)d_in[7];
    const float* convb2 = (const float*)d_in[8];
    const float* mlpW1  = (const float*)d_in[9];
    const float* mlpb1  = (const float*)d_in[10];
    const float* mlpg   = (const float*)d_in[11];
    const float* mlpbt  = (const float*)d_in[12];
    const float* mlpW2  = (const float*)d_in[13];
    const float* mlpb2  = (const float*)d_in[14];

    const int N = in_sizes[0] / F;             // 50000
    const int E = in_sizes[1] / 2;             // 800000
    const int L = in_sizes[3] / (F * F);       // 5

    const int* src = ei;
    const int* dst = ei + E;

    char* w = (char*)d_ws;
    size_t off = 0;
    auto alloc = [&](size_t bytes) {
        void* p = w + off;
        off = (off + bytes + 255) & ~(size_t)255;
        return p;
    };
    u16*   x16     = (u16*)alloc((size_t)N * F * 2);
    u16*   hA16    = (u16*)alloc((size_t)N * F * 2);
    u16*   hB16    = (u16*)alloc((size_t)N * F * 2);
    float* Ytmp    = (float*)alloc((size_t)N * F * 4);
    float* Yf      = (float*)alloc((size_t)N * F * 4);
    int*   deg     = (int*)alloc((size_t)N * 4);
    int*   offs    = (int*)alloc((size_t)(N + 1) * 4);
    int*   cursor  = (int*)alloc((size_t)N * 4);
    int*   csr_src = (int*)alloc((size_t)E * 4);
    int*   part    = (int*)alloc((size_t)SCAN_B * 4);
    float* stats   = (float*)alloc((size_t)(L + 1) * 128 * 4);

    hipMemsetAsync(deg, 0, (size_t)N * 4, stream);
    hipMemsetAsync(stats, 0, (size_t)(L + 1) * 128 * 4, stream);
    hipMemsetAsync(d_out, 0, (size_t)out_size * 4, stream);

    const int edgeBlocks = (E + TPB - 1) / TPB;

    k_hist<<<edgeBlocks, TPB, 0, stream>>>(dst, deg, E);
    k_scan_part<<<SCAN_B, TPB, 0, stream>>>(deg, part, N);
    k_scan_apply<<<SCAN_B, TPB, 0, stream>>>(deg, part, offs, cursor, N);
    k_fill<<<edgeBlocks, TPB, 0, stream>>>(src, dst, cursor, csr_src, E);

    const int NPW_A = 8;
    const int RPW   = 8;
    const int RPW_F = 16;
    const int blocksA = (N + 4 * NPW_A - 1) / (4 * NPW_A);
    const int blocksD = (N + 4 * RPW - 1) / (4 * RPW);
    const int blocksF = (N + 4 * RPW_F - 1) / (4 * RPW_F);

    // fused bf16-convert + JK-init (reads x once)
    k_prep<<<blocksD, TPB, 0, stream>>>(x, x16, mlpW1, mlpb1, Yf, N, RPW);

    const u16* h_cur = x16;
    for (int l = 0; l < L; ++l) {
        u16* h_next = (l & 1) ? hB16 : hA16;
        k_gather_gemm<<<blocksA, TPB, 0, stream>>>(h_cur, offs, csr_src,
                                                   convW1 + l * F * F, convb1 + l * F,
                                                   Ytmp, stats + l * 128, N, NPW_A);
        k_layerB<<<blocksD, TPB, 0, stream>>>(Ytmp, stats + l * 128,
                                              convg + l * F, convbt + l * F,
                                              convW2 + l * F * F, convb2 + l * F,
                                              mlpW1 + (l + 1) * F * F,
                                              h_next, Yf, stats + L * 128,
                                              N, RPW, l == L - 1);
        h_cur = h_next;
    }

    k_final<<<blocksF, TPB, 0, stream>>>(Yf, stats + L * 128, mlpg, mlpbt,
                                         mlpW2, mlpb2, batch, (float*)d_out, N, RPW_F);
}